// Round 2
// baseline (45990.536 us; speedup 1.0000x reference)
//
#include <hip/hip_runtime.h>
#include <hip/hip_bf16.h>
#include <cmath>

#define NB 8
#define NS 512
#define NHID 768
#define NHEAD 12
#define NL 12
#define NDH 64
#define NFF 3072
#define NTOK (NB*NS)
#define LN_EPS 1e-7f

static __device__ __forceinline__ void loadA4(const float* p, float* av){
  float4 t = *(const float4*)p;
  av[0]=t.x; av[1]=t.y; av[2]=t.z; av[3]=t.w;
}

// ---------------- embedding: gather + LN + mask ----------------
__global__ __launch_bounds__(256) void emb_kernel(
    const float* __restrict__ we, const float* __restrict__ pe,
    const float* __restrict__ g, const float* __restrict__ bvec,
    const int* __restrict__ ids, const int* __restrict__ msk, float* __restrict__ out)
{
  const int token = blockIdx.x, tid = threadIdx.x;
  const int s = token & (NS-1);
  __shared__ float red[256];
  const int id = ids[token];
  const float* wp = we + (size_t)id*NHID;
  const float* pp = pe + (size_t)s*NHID;
  float e[3]; float sum = 0.f;
  #pragma unroll
  for (int j=0;j<3;j++){ int d = tid + j*256; e[j] = wp[d] + pp[d]; sum += e[j]; }
  red[tid]=sum; __syncthreads();
  for (int o=128;o>0;o>>=1){ if (tid<o) red[tid]+=red[tid+o]; __syncthreads(); }
  const float mu = red[0]*(1.0f/NHID); __syncthreads();
  float vs=0.f;
  #pragma unroll
  for (int j=0;j<3;j++){ float d=e[j]-mu; vs += d*d; }
  red[tid]=vs; __syncthreads();
  for (int o=128;o>0;o>>=1){ if (tid<o) red[tid]+=red[tid+o]; __syncthreads(); }
  const float rstd = 1.0f/sqrtf(red[0]*(1.0f/NHID)+LN_EPS);
  const float mf = (float)msk[token];
  #pragma unroll
  for (int j=0;j<3;j++){
    int d = tid + j*256;
    out[(size_t)token*NHID + d] = ((e[j]-mu)*rstd*g[d] + bvec[d])*mf;
  }
}

// ---------------- LayerNorm (f32 in, f32 out) ----------------
__global__ __launch_bounds__(256) void ln_kernel(
    const float* __restrict__ X, const float* __restrict__ g, const float* __restrict__ bvec,
    float* __restrict__ out)
{
  const int token = blockIdx.x, tid = threadIdx.x;
  __shared__ float red[256];
  const float* x = X + (size_t)token*NHID;
  float e[3]; float sum=0.f;
  #pragma unroll
  for (int j=0;j<3;j++){ e[j]=x[tid+j*256]; sum+=e[j]; }
  red[tid]=sum; __syncthreads();
  for (int o=128;o>0;o>>=1){ if (tid<o) red[tid]+=red[tid+o]; __syncthreads(); }
  const float mu = red[0]*(1.0f/NHID); __syncthreads();
  float vs=0.f;
  #pragma unroll
  for (int j=0;j<3;j++){ float d=e[j]-mu; vs+=d*d; }
  red[tid]=vs; __syncthreads();
  for (int o=128;o>0;o>>=1){ if (tid<o) red[tid]+=red[tid+o]; __syncthreads(); }
  const float rstd = 1.0f/sqrtf(red[0]*(1.0f/NHID)+LN_EPS);
  #pragma unroll
  for (int j=0;j<3;j++){
    int d = tid + j*256;
    out[(size_t)token*NHID + d] = (e[j]-mu)*rstd*g[d] + bvec[d];
  }
}

// ---------------- GEMM: C[M,N] = epi(A[M,K] @ W[K,N] + bias) ----------------
// EPI: 0=none, 1=exact GELU, 2=+res
template<int EPI>
__global__ __launch_bounds__(256) void gemm_kernel(
    const float* __restrict__ A, const float* __restrict__ W, const float* __restrict__ bias,
    const float* __restrict__ res, float* __restrict__ outp, int M, int N, int K)
{
  __shared__ __align__(16) float As[16][68];
  __shared__ __align__(16) float Bs[16][68];
  const int tid = threadIdx.x;
  const int bm = blockIdx.y*64, bn = blockIdx.x*64;
  const int tx = tid&15, ty = tid>>4;
  const int am = tid>>2, ak = (tid&3)*4;
  const int bkr = tid>>4, bnc = (tid&15)*4;
  float acc[4][4] = {};
  const float* Ap = A + (size_t)(bm+am)*K + ak;
  const float* Wp = W + (size_t)bkr*N + bn + bnc;
  for (int kt=0; kt<K; kt+=16){
    float av[4]; loadA4(Ap + kt, av);
    float wv[4]; loadA4(Wp + (size_t)kt*N, wv);
    __syncthreads();
    As[ak+0][am]=av[0]; As[ak+1][am]=av[1]; As[ak+2][am]=av[2]; As[ak+3][am]=av[3];
    *(float4*)&Bs[bkr][bnc] = make_float4(wv[0],wv[1],wv[2],wv[3]);
    __syncthreads();
    #pragma unroll
    for (int kk=0;kk<16;kk++){
      float4 a4 = *(const float4*)&As[kk][ty*4];
      float4 b4 = *(const float4*)&Bs[kk][tx*4];
      float aa[4]={a4.x,a4.y,a4.z,a4.w};
      float bb[4]={b4.x,b4.y,b4.z,b4.w};
      #pragma unroll
      for (int i=0;i<4;i++)
        #pragma unroll
        for (int j=0;j<4;j++)
          acc[i][j] += aa[i]*bb[j];
    }
  }
  float bv[4]; loadA4(bias + bn + tx*4, bv);
  #pragma unroll
  for (int i=0;i<4;i++){
    const int m = bm + ty*4 + i;
    #pragma unroll
    for (int j=0;j<4;j++){
      const int n = bn + tx*4 + j;
      float v = acc[i][j] + bv[j];
      if (EPI==1) v = 0.5f*v*(1.0f + erff(v*0.7071067811865476f));
      if (EPI==2) v += res[(size_t)m*N + n];
      outp[(size_t)m*N + n] = v;
    }
  }
}

// ---------------- fused disentangled attention ----------------
// one block per (b, h, q): scores(qk + c2p + p2c) -> masked softmax -> probs @ V
__global__ __launch_bounds__(256) void attn_kernel(
    const float* __restrict__ Q, const float* __restrict__ K, const float* __restrict__ V,
    const float* __restrict__ PK, const float* __restrict__ PQ,
    const int* __restrict__ msk, float* __restrict__ Ctx)
{
  const int q = blockIdx.x, h = blockIdx.y, b = blockIdx.z;
  const int tid = threadIdx.x;
  __shared__ float qv[NDH];
  __shared__ float c2p[512];
  __shared__ float sc[NS];
  __shared__ float red[256];
  const size_t rowq = (size_t)(b*NS+q)*NHID + h*NDH;
  if (tid < NDH) qv[tid] = Q[rowq + tid];
  __syncthreads();
  // phase 1: c2p row: q . pos_k[m]
  for (int m=tid; m<512; m+=256){
    const float4* pr = (const float4*)(PK + (size_t)m*NHID + h*NDH);
    float dot = 0.f;
    #pragma unroll
    for (int c=0;c<16;c++){
      float4 f = pr[c];
      dot += qv[c*4+0]*f.x + qv[c*4+1]*f.y + qv[c*4+2]*f.z + qv[c*4+3]*f.w;
    }
    c2p[m] = dot;
  }
  __syncthreads();
  const int mq = msk[b*NS+q];
  // phase 2: scores (bucket(q-k) serves BOTH c2p and p2c gathers — antisymmetric)
  for (int k=tid; k<NS; k+=256){
    const int rel = q - k;
    const int sg = (rel>0) - (rel<0);
    const float ap = (rel<128 && rel>-128) ? 127.0f : fabsf((float)rel);
    int bucket;
    if (ap <= 128.0f) bucket = rel;
    else bucket = (int)((ceilf(logf(ap*(1.0f/128.0f))/1.3843393f*127.0f)+128.0f)*(float)sg);
    const int idx = min(max(bucket+256,0),511);
    const float4* kp = (const float4*)(K + (size_t)(b*NS+k)*NHID + h*NDH);
    const float4* pp = (const float4*)(PQ + (size_t)idx*NHID + h*NDH);
    float qk=0.f, pc=0.f;
    #pragma unroll
    for (int c=0;c<16;c++){
      float4 kf = kp[c]; float4 pf = pp[c];
      qk += qv[c*4+0]*kf.x + qv[c*4+1]*kf.y + qv[c*4+2]*kf.z + qv[c*4+3]*kf.w;
      pc += kf.x*pf.x + kf.y*pf.y + kf.z*pf.z + kf.w*pf.w;
    }
    const float s = (qk + c2p[idx] + pc) * 0.07216878364870322f; // 1/sqrt(3*DH)
    const int mk = msk[b*NS+k];
    sc[k] = (mq!=0 && mk!=0) ? s : -3.402823466e38f;
  }
  __syncthreads();
  // phase 3: masked softmax
  float lm = fmaxf(sc[tid], sc[tid+256]);
  red[tid]=lm; __syncthreads();
  for (int o=128;o>0;o>>=1){ if (tid<o) red[tid]=fmaxf(red[tid],red[tid+o]); __syncthreads(); }
  const float mx = red[0]; __syncthreads();
  float ps = 0.f;
  for (int k=tid; k<NS; k+=256){
    const int mk = msk[b*NS+k];
    float p = (mq!=0 && mk!=0) ? expf(sc[k]-mx) : 0.0f;
    sc[k] = p; ps += p;
  }
  red[tid]=ps; __syncthreads();
  for (int o=128;o>0;o>>=1){ if (tid<o) red[tid]+=red[tid+o]; __syncthreads(); }
  const float sum = red[0];
  const float inv = sum>0.f ? 1.0f/sum : 0.0f;
  __syncthreads();
  for (int k=tid; k<NS; k+=256) sc[k] *= inv;
  __syncthreads();
  // phase 4: ctx = probs @ V
  const int d = tid & 63, ch = tid >> 6;
  const float* vp = V + (size_t)(b*NS + ch*128)*NHID + h*NDH + d;
  float part = 0.f;
  for (int kk=0; kk<128; kk++) part += sc[ch*128+kk]*vp[(size_t)kk*NHID];
  red[tid]=part; __syncthreads();
  if (tid < 64){
    float v = red[tid]+red[tid+64]+red[tid+128]+red[tid+192];
    Ctx[rowq + tid] = v;
  }
}

extern "C" void kernel_launch(void* const* d_in, const int* in_sizes, int n_in,
                              void* d_out, int out_size, void* d_ws, size_t ws_size,
                              hipStream_t stream)
{
  const float* word_emb=(const float*)d_in[0];
  const float* pos_emb =(const float*)d_in[1];
  const float* emb_g   =(const float*)d_in[2];
  const float* emb_b   =(const float*)d_in[3];
  const float* rel_emb =(const float*)d_in[4];
  const float* Wq=(const float*)d_in[5];  const float* bq=(const float*)d_in[6];
  const float* Wk=(const float*)d_in[7];  const float* bk=(const float*)d_in[8];
  const float* Wv=(const float*)d_in[9];  const float* bvv=(const float*)d_in[10];
  const float* Wo=(const float*)d_in[11]; const float* bo=(const float*)d_in[12];
  const float* g1=(const float*)d_in[13]; const float* b1=(const float*)d_in[14];
  const float* Wi=(const float*)d_in[15]; const float* bi=(const float*)d_in[16];
  const float* Wo2=(const float*)d_in[17];const float* bo2=(const float*)d_in[18];
  const float* g2=(const float*)d_in[19]; const float* b2=(const float*)d_in[20];
  const int* ids  =(const int*)d_in[21];
  const int* amask=(const int*)d_in[22];

  char* p = (char*)d_ws;
  auto alloc = [&](size_t bytes)->char*{ char* r = p; p += (bytes + 255) & ~(size_t)255; return r; };
  float* Hb  = (float*)alloc((size_t)NTOK*NHID*4);
  float* H1  = (float*)alloc((size_t)NTOK*NHID*4);
  float* Xb  = (float*)alloc((size_t)NTOK*NHID*4);
  float* FFb = (float*)alloc((size_t)NTOK*NFF*4);
  float* Ctxb= (float*)alloc((size_t)NTOK*NHID*4);
  float* Qb  = (float*)alloc((size_t)NTOK*NHID*4);
  float* Kb  = (float*)alloc((size_t)NTOK*NHID*4);
  float* Vb  = (float*)alloc((size_t)NTOK*NHID*4);
  float* PKb = (float*)alloc((size_t)512*NHID*4);
  float* PQb = (float*)alloc((size_t)512*NHID*4);

  dim3 blk(256);
  dim3 gQ(NHID/64, NTOK/64);   // 12 x 64
  dim3 gP(NHID/64, NS/64);     // 12 x 8
  dim3 gF1(NFF/64, NTOK/64);   // 48 x 64
  dim3 gAttn(NS, NHEAD, NB);

  emb_kernel<<<NTOK,blk,0,stream>>>(word_emb,pos_emb,emb_g,emb_b,ids,amask,Hb);

  for (int l=0; l<NL; l++){
    const float *Wq_l=Wq+(size_t)l*NHID*NHID, *bq_l=bq+(size_t)l*NHID;
    const float *Wk_l=Wk+(size_t)l*NHID*NHID, *bk_l=bk+(size_t)l*NHID;
    const float *Wv_l=Wv+(size_t)l*NHID*NHID, *bv_l=bvv+(size_t)l*NHID;
    const float *Wo_l=Wo+(size_t)l*NHID*NHID, *bo_l=bo+(size_t)l*NHID;
    const float *g1_l=g1+(size_t)l*NHID, *b1_l=b1+(size_t)l*NHID;
    const float *Wi_l=Wi+(size_t)l*NHID*NFF, *bi_l=bi+(size_t)l*NFF;
    const float *Wo2_l=Wo2+(size_t)l*NFF*NHID, *bo2_l=bo2+(size_t)l*NHID;
    const float *g2_l=g2+(size_t)l*NHID, *b2_l=b2+(size_t)l*NHID;

    // relative position projections (share_att_key=True: use Wk/Wq)
    gemm_kernel<0><<<gP,blk,0,stream>>>(rel_emb, Wk_l, bk_l, nullptr, PKb, 512,NHID,NHID);
    gemm_kernel<0><<<gP,blk,0,stream>>>(rel_emb, Wq_l, bq_l, nullptr, PQb, 512,NHID,NHID);
    // Q,K,V
    gemm_kernel<0><<<gQ,blk,0,stream>>>(Hb, Wq_l, bq_l, nullptr, Qb, NTOK,NHID,NHID);
    gemm_kernel<0><<<gQ,blk,0,stream>>>(Hb, Wk_l, bk_l, nullptr, Kb, NTOK,NHID,NHID);
    gemm_kernel<0><<<gQ,blk,0,stream>>>(Hb, Wv_l, bv_l, nullptr, Vb, NTOK,NHID,NHID);
    // attention
    attn_kernel<<<gAttn,blk,0,stream>>>(Qb,Kb,Vb,PKb,PQb,amask,Ctxb);
    // output proj + residual, LN1
    gemm_kernel<2><<<gQ,blk,0,stream>>>(Ctxb, Wo_l, bo_l, Hb, Xb, NTOK,NHID,NHID);
    ln_kernel<<<NTOK,blk,0,stream>>>(Xb, g1_l, b1_l, H1);
    // FFN
    gemm_kernel<1><<<gF1,blk,0,stream>>>(H1, Wi_l, bi_l, nullptr, FFb, NTOK,NFF,NHID);
    gemm_kernel<2><<<gQ,blk,0,stream>>>(FFb, Wo2_l, bo2_l, H1, Xb, NTOK,NHID,NFF);
    // LN2: last layer writes the final output directly
    float* dst = (l==NL-1) ? (float*)d_out : Hb;
    ln_kernel<<<NTOK,blk,0,stream>>>(Xb, g2_l, b2_l, dst);
  }
}

// Round 4
// 16192.331 us; speedup vs baseline: 2.8403x; 2.8403x over previous
//
#include <hip/hip_runtime.h>
#include <hip/hip_bf16.h>
#include <cmath>

#define NB 8
#define NS 512
#define NHID 768
#define NHEAD 12
#define NL 12
#define NDH 64
#define NFF 3072
#define NTOK (NB*NS)
#define LN_EPS 1e-7f
#define NREL 1023

static __device__ __forceinline__ void loadA4(const float* p, float* av){
  float4 t = *(const float4*)p;
  av[0]=t.x; av[1]=t.y; av[2]=t.z; av[3]=t.w;
}
static __device__ __forceinline__ float dot4(float4 a, float4 b){
  return a.x*b.x + a.y*b.y + a.z*b.z + a.w*b.w;
}

// ---------------- embedding: gather + LN + mask ----------------
__global__ __launch_bounds__(256) void emb_kernel(
    const float* __restrict__ we, const float* __restrict__ pe,
    const float* __restrict__ g, const float* __restrict__ bvec,
    const int* __restrict__ ids, const int* __restrict__ msk, float* __restrict__ out)
{
  const int token = blockIdx.x, tid = threadIdx.x;
  const int s = token & (NS-1);
  __shared__ float red[256];
  const int id = ids[token];
  const float* wp = we + (size_t)id*NHID;
  const float* pp = pe + (size_t)s*NHID;
  float e[3]; float sum = 0.f;
  #pragma unroll
  for (int j=0;j<3;j++){ int d = tid + j*256; e[j] = wp[d] + pp[d]; sum += e[j]; }
  red[tid]=sum; __syncthreads();
  for (int o=128;o>0;o>>=1){ if (tid<o) red[tid]+=red[tid+o]; __syncthreads(); }
  const float mu = red[0]*(1.0f/NHID); __syncthreads();
  float vs=0.f;
  #pragma unroll
  for (int j=0;j<3;j++){ float d=e[j]-mu; vs += d*d; }
  red[tid]=vs; __syncthreads();
  for (int o=128;o>0;o>>=1){ if (tid<o) red[tid]+=red[tid+o]; __syncthreads(); }
  const float rstd = 1.0f/sqrtf(red[0]*(1.0f/NHID)+LN_EPS);
  const float mf = (float)msk[token];
  #pragma unroll
  for (int j=0;j<3;j++){
    int d = tid + j*256;
    out[(size_t)token*NHID + d] = ((e[j]-mu)*rstd*g[d] + bvec[d])*mf;
  }
}

// ---------------- LayerNorm (f32 in, f32 out) ----------------
__global__ __launch_bounds__(256) void ln_kernel(
    const float* __restrict__ X, const float* __restrict__ g, const float* __restrict__ bvec,
    float* __restrict__ out)
{
  const int token = blockIdx.x, tid = threadIdx.x;
  __shared__ float red[256];
  const float* x = X + (size_t)token*NHID;
  float e[3]; float sum=0.f;
  #pragma unroll
  for (int j=0;j<3;j++){ e[j]=x[tid+j*256]; sum+=e[j]; }
  red[tid]=sum; __syncthreads();
  for (int o=128;o>0;o>>=1){ if (tid<o) red[tid]+=red[tid+o]; __syncthreads(); }
  const float mu = red[0]*(1.0f/NHID); __syncthreads();
  float vs=0.f;
  #pragma unroll
  for (int j=0;j<3;j++){ float d=e[j]-mu; vs+=d*d; }
  red[tid]=vs; __syncthreads();
  for (int o=128;o>0;o>>=1){ if (tid<o) red[tid]+=red[tid+o]; __syncthreads(); }
  const float rstd = 1.0f/sqrtf(red[0]*(1.0f/NHID)+LN_EPS);
  #pragma unroll
  for (int j=0;j<3;j++){
    int d = tid + j*256;
    out[(size_t)token*NHID + d] = (e[j]-mu)*rstd*g[d] + bvec[d];
  }
}

// ---------------- GEMM: C[M,N] = epi(A[M,K] @ W[K,N] + bias) ----------------
// EPI: 0=none, 1=exact GELU, 2=+res
template<int EPI>
__global__ __launch_bounds__(256) void gemm_kernel(
    const float* __restrict__ A, const float* __restrict__ W, const float* __restrict__ bias,
    const float* __restrict__ res, float* __restrict__ outp, int M, int N, int K)
{
  __shared__ __align__(16) float As[16][68];
  __shared__ __align__(16) float Bs[16][68];
  const int tid = threadIdx.x;
  const int bm = blockIdx.y*64, bn = blockIdx.x*64;
  const int tx = tid&15, ty = tid>>4;
  const int am = tid>>2, ak = (tid&3)*4;
  const int bkr = tid>>4, bnc = (tid&15)*4;
  float acc[4][4] = {};
  const float* Ap = A + (size_t)(bm+am)*K + ak;
  const float* Wp = W + (size_t)bkr*N + bn + bnc;
  for (int kt=0; kt<K; kt+=16){
    float av[4]; loadA4(Ap + kt, av);
    float wv[4]; loadA4(Wp + (size_t)kt*N, wv);
    __syncthreads();
    As[ak+0][am]=av[0]; As[ak+1][am]=av[1]; As[ak+2][am]=av[2]; As[ak+3][am]=av[3];
    *(float4*)&Bs[bkr][bnc] = make_float4(wv[0],wv[1],wv[2],wv[3]);
    __syncthreads();
    #pragma unroll
    for (int kk=0;kk<16;kk++){
      float4 a4 = *(const float4*)&As[kk][ty*4];
      float4 b4 = *(const float4*)&Bs[kk][tx*4];
      float aa[4]={a4.x,a4.y,a4.z,a4.w};
      float bb[4]={b4.x,b4.y,b4.z,b4.w};
      #pragma unroll
      for (int i=0;i<4;i++)
        #pragma unroll
        for (int j=0;j<4;j++)
          acc[i][j] += aa[i]*bb[j];
    }
  }
  float bv[4]; loadA4(bias + bn + tx*4, bv);
  #pragma unroll
  for (int i=0;i<4;i++){
    const int m = bm + ty*4 + i;
    #pragma unroll
    for (int j=0;j<4;j++){
      const int n = bn + tx*4 + j;
      float v = acc[i][j] + bv[j];
      if (EPI==1) v = 0.5f*v*(1.0f + erff(v*0.7071067811865476f));
      if (EPI==2) v += res[(size_t)m*N + n];
      outp[(size_t)m*N + n] = v;
    }
  }
}

// ---------------- rel-position pre-gather: PKg[h][r][d] = PK[idx(r-511)][h*64+d] ----------------
__global__ __launch_bounds__(64) void relgather_kernel(
    const float* __restrict__ PKb, const float* __restrict__ PQb,
    float* __restrict__ PKg, float* __restrict__ PQg)
{
  const int r = blockIdx.x;       // 0..1022
  const int h = blockIdx.y;       // 0..11
  const int d = threadIdx.x;      // 0..63
  const int rel = r - 511;
  const int sg = (rel>0) - (rel<0);
  const float ap = (rel<128 && rel>-128) ? 127.0f : fabsf((float)rel);
  int bucket;
  if (ap <= 128.0f) bucket = rel;
  else bucket = (int)((ceilf(logf(ap*(1.0f/128.0f))/1.3843393f*127.0f)+128.0f)*(float)sg);
  const int idx = min(max(bucket+256,0),511);
  const size_t src = (size_t)idx*NHID + h*NDH + d;
  const size_t dst = ((size_t)h*NREL + r)*NDH + d;
  PKg[dst] = PKb[src];
  PQg[dst] = PQb[src];
}

// ---------------- tiled flash-style disentangled attention ----------------
// block = (qtile of 32, h, b). score(q,k) = Q.K + Q.PKg[q-k] + K.PQg[q-k]
#define QT 32
#define KT 32
#define RT 63
__global__ __launch_bounds__(256) void attn_kernel(
    const float* __restrict__ Q, const float* __restrict__ K, const float* __restrict__ V,
    const float* __restrict__ PKg, const float* __restrict__ PQg,
    const int* __restrict__ msk, float* __restrict__ Ctx)
{
  __shared__ __align__(16) float Qs[QT][68];
  __shared__ __align__(16) float Ks[KT][68];
  __shared__ __align__(16) float Vs[KT][68];
  __shared__ __align__(16) float PKs[RT][68];
  __shared__ __align__(16) float PQs[RT][68];
  __shared__ __align__(16) float Ss[QT][36];
  __shared__ int mqS[QT];
  __shared__ int mkS[KT];
  const int tid = threadIdx.x;
  const int qt = blockIdx.x, h = blockIdx.y, b = blockIdx.z;
  const int q0 = qt*QT;
  // stage Q tile + q-mask
  for (int i = tid; i < QT*16; i += 256){
    int row = i>>4, c = (i&15)*4;
    *(float4*)&Qs[row][c] = *(const float4*)&Q[(size_t)(b*NS + q0 + row)*NHID + h*NDH + c];
  }
  if (tid < QT) mqS[tid] = msk[b*NS + q0 + tid];

  const int tx = tid & 15, ty = tid >> 4;     // score phase: 2x2 per thread
  const int sq = tid >> 3, sj = tid & 7;      // softmax/PV phase: 8 threads per q-row
  const int dj = sj*8;
  float m_i = -3.4e38f, l_i = 0.f;
  float ctx[8] = {0,0,0,0,0,0,0,0};

  for (int kt = 0; kt < NS/KT; kt++){
    const int k0c = kt*KT;
    __syncthreads();   // previous iteration's readers done
    for (int i = tid; i < KT*16; i += 256){
      int row = i>>4, c = (i&15)*4;
      size_t gb = (size_t)(b*NS + k0c + row)*NHID + h*NDH + c;
      *(float4*)&Ks[row][c] = *(const float4*)&K[gb];
      *(float4*)&Vs[row][c] = *(const float4*)&V[gb];
    }
    const int rstart = q0 - k0c + 480;  // global rel-row of local rel 0
    for (int i = tid; i < RT*16; i += 256){
      int row = i>>4, c = (i&15)*4;
      size_t gb = ((size_t)h*NREL + rstart + row)*NDH + c;
      *(float4*)&PKs[row][c] = *(const float4*)&PKg[gb];
      *(float4*)&PQs[row][c] = *(const float4*)&PQg[gb];
    }
    if (tid < KT) mkS[tid] = msk[b*NS + k0c + tid];
    __syncthreads();
    // ---- scores: 2x2 microtile ----
    const int qa = ty*2, kb = tx*2;
    const int rc = qa - kb + 31;  // local rel of (qa,kb); (qa,kb+1)->rc-1; (qa+1,kb)->rc+1
    float s00=0,s01=0,s10=0,s11=0;
    #pragma unroll
    for (int c = 0; c < 64; c += 4){
      float4 qv0 = *(const float4*)&Qs[qa  ][c];
      float4 qv1 = *(const float4*)&Qs[qa+1][c];
      float4 kv0 = *(const float4*)&Ks[kb  ][c];
      float4 kv1 = *(const float4*)&Ks[kb+1][c];
      float4 pk0 = *(const float4*)&PKs[rc-1][c];
      float4 pk1 = *(const float4*)&PKs[rc  ][c];
      float4 pk2 = *(const float4*)&PKs[rc+1][c];
      float4 pq0 = *(const float4*)&PQs[rc-1][c];
      float4 pq1 = *(const float4*)&PQs[rc  ][c];
      float4 pq2 = *(const float4*)&PQs[rc+1][c];
      s00 += dot4(qv0,kv0) + dot4(qv0,pk1) + dot4(kv0,pq1);
      s01 += dot4(qv0,kv1) + dot4(qv0,pk0) + dot4(kv1,pq0);
      s10 += dot4(qv1,kv0) + dot4(qv1,pk2) + dot4(kv0,pq2);
      s11 += dot4(qv1,kv1) + dot4(qv1,pk1) + dot4(kv1,pq1);
    }
    const float SC = 0.07216878364870322f; // 1/sqrt(3*64)
    const int mq0=mqS[qa], mq1=mqS[qa+1], mk0=mkS[kb], mk1=mkS[kb+1];
    Ss[qa  ][kb  ] = (mq0&&mk0)? s00*SC : -3.4e38f;
    Ss[qa  ][kb+1] = (mq0&&mk1)? s01*SC : -3.4e38f;
    Ss[qa+1][kb  ] = (mq1&&mk0)? s10*SC : -3.4e38f;
    Ss[qa+1][kb+1] = (mq1&&mk1)? s11*SC : -3.4e38f;
    __syncthreads();
    // ---- online softmax update (8 lanes per row, same wave) ----
    float4 sp = *(const float4*)&Ss[sq][sj*4];
    float tm = fmaxf(fmaxf(sp.x,sp.y), fmaxf(sp.z,sp.w));
    tm = fmaxf(tm, __shfl_xor(tm, 1, 8));
    tm = fmaxf(tm, __shfl_xor(tm, 2, 8));
    tm = fmaxf(tm, __shfl_xor(tm, 4, 8));
    const float m_new = fmaxf(m_i, tm);
    const float alpha = expf(m_i - m_new);
    float p0 = expf(sp.x - m_new), p1 = expf(sp.y - m_new);
    float p2 = expf(sp.z - m_new), p3 = expf(sp.w - m_new);
    *(float4*)&Ss[sq][sj*4] = make_float4(p0,p1,p2,p3);
    float ts = p0+p1+p2+p3;
    ts += __shfl_xor(ts, 1, 8);
    ts += __shfl_xor(ts, 2, 8);
    ts += __shfl_xor(ts, 4, 8);
    l_i = l_i*alpha + ts;
    m_i = m_new;
    __syncthreads();
    // ---- PV accumulate ----
    #pragma unroll
    for (int e=0;e<8;e++) ctx[e] *= alpha;
    #pragma unroll
    for (int k=0;k<KT;k+=4){
      float4 pv = *(const float4*)&Ss[sq][k];
      #pragma unroll
      for (int kk=0;kk<4;kk++){
        const float p = (kk==0)?pv.x:(kk==1)?pv.y:(kk==2)?pv.z:pv.w;
        float4 va = *(const float4*)&Vs[k+kk][dj];
        float4 vb = *(const float4*)&Vs[k+kk][dj+4];
        ctx[0]+=p*va.x; ctx[1]+=p*va.y; ctx[2]+=p*va.z; ctx[3]+=p*va.w;
        ctx[4]+=p*vb.x; ctx[5]+=p*vb.y; ctx[6]+=p*vb.z; ctx[7]+=p*vb.w;
      }
    }
  }
  const float inv = (l_i > 0.f && m_i > -1e30f && mqS[sq]) ? 1.0f/l_i : 0.0f;
  const size_t orow = (size_t)(b*NS + q0 + sq)*NHID + h*NDH + dj;
  #pragma unroll
  for (int e=0;e<8;e++) Ctx[orow+e] = ctx[e]*inv;
}

extern "C" void kernel_launch(void* const* d_in, const int* in_sizes, int n_in,
                              void* d_out, int out_size, void* d_ws, size_t ws_size,
                              hipStream_t stream)
{
  const float* word_emb=(const float*)d_in[0];
  const float* pos_emb =(const float*)d_in[1];
  const float* emb_g   =(const float*)d_in[2];
  const float* emb_b   =(const float*)d_in[3];
  const float* rel_emb =(const float*)d_in[4];
  const float* Wq=(const float*)d_in[5];  const float* bq=(const float*)d_in[6];
  const float* Wk=(const float*)d_in[7];  const float* bk=(const float*)d_in[8];
  const float* Wv=(const float*)d_in[9];  const float* bvv=(const float*)d_in[10];
  const float* Wo=(const float*)d_in[11]; const float* bo=(const float*)d_in[12];
  const float* g1=(const float*)d_in[13]; const float* b1=(const float*)d_in[14];
  const float* Wi=(const float*)d_in[15]; const float* bi=(const float*)d_in[16];
  const float* Wo2=(const float*)d_in[17];const float* bo2=(const float*)d_in[18];
  const float* g2=(const float*)d_in[19]; const float* b2=(const float*)d_in[20];
  const int* ids  =(const int*)d_in[21];
  const int* amask=(const int*)d_in[22];

  char* p = (char*)d_ws;
  auto alloc = [&](size_t bytes)->char*{ char* r = p; p += (bytes + 255) & ~(size_t)255; return r; };
  float* Hb  = (float*)alloc((size_t)NTOK*NHID*4);
  float* H1  = (float*)alloc((size_t)NTOK*NHID*4);
  float* Xb  = (float*)alloc((size_t)NTOK*NHID*4);
  float* FFb = (float*)alloc((size_t)NTOK*NFF*4);
  float* Ctxb= (float*)alloc((size_t)NTOK*NHID*4);
  float* Qb  = (float*)alloc((size_t)NTOK*NHID*4);
  float* Kb  = (float*)alloc((size_t)NTOK*NHID*4);
  float* Vb  = (float*)alloc((size_t)NTOK*NHID*4);
  float* PKb = (float*)alloc((size_t)512*NHID*4);
  float* PQb = (float*)alloc((size_t)512*NHID*4);
  float* PKg = (float*)alloc((size_t)NHEAD*NREL*NDH*4);
  float* PQg = (float*)alloc((size_t)NHEAD*NREL*NDH*4);

  dim3 blk(256);
  dim3 gQ(NHID/64, NTOK/64);   // 12 x 64
  dim3 gP(NHID/64, NS/64);     // 12 x 8
  dim3 gF1(NFF/64, NTOK/64);   // 48 x 64
  dim3 gRel(NREL, NHEAD);
  dim3 gAttn(NS/QT, NHEAD, NB);

  emb_kernel<<<NTOK,blk,0,stream>>>(word_emb,pos_emb,emb_g,emb_b,ids,amask,Hb);

  for (int l=0; l<NL; l++){
    const float *Wq_l=Wq+(size_t)l*NHID*NHID, *bq_l=bq+(size_t)l*NHID;
    const float *Wk_l=Wk+(size_t)l*NHID*NHID, *bk_l=bk+(size_t)l*NHID;
    const float *Wv_l=Wv+(size_t)l*NHID*NHID, *bv_l=bvv+(size_t)l*NHID;
    const float *Wo_l=Wo+(size_t)l*NHID*NHID, *bo_l=bo+(size_t)l*NHID;
    const float *g1_l=g1+(size_t)l*NHID, *b1_l=b1+(size_t)l*NHID;
    const float *Wi_l=Wi+(size_t)l*NHID*NFF, *bi_l=bi+(size_t)l*NFF;
    const float *Wo2_l=Wo2+(size_t)l*NFF*NHID, *bo2_l=bo2+(size_t)l*NHID;
    const float *g2_l=g2+(size_t)l*NHID, *b2_l=b2+(size_t)l*NHID;

    // relative position projections (share_att_key=True: use Wk/Wq), then pre-gather by rel
    gemm_kernel<0><<<gP,blk,0,stream>>>(rel_emb, Wk_l, bk_l, nullptr, PKb, 512,NHID,NHID);
    gemm_kernel<0><<<gP,blk,0,stream>>>(rel_emb, Wq_l, bq_l, nullptr, PQb, 512,NHID,NHID);
    relgather_kernel<<<gRel,dim3(64),0,stream>>>(PKb, PQb, PKg, PQg);
    // Q,K,V
    gemm_kernel<0><<<gQ,blk,0,stream>>>(Hb, Wq_l, bq_l, nullptr, Qb, NTOK,NHID,NHID);
    gemm_kernel<0><<<gQ,blk,0,stream>>>(Hb, Wk_l, bk_l, nullptr, Kb, NTOK,NHID,NHID);
    gemm_kernel<0><<<gQ,blk,0,stream>>>(Hb, Wv_l, bv_l, nullptr, Vb, NTOK,NHID,NHID);
    // attention
    attn_kernel<<<gAttn,blk,0,stream>>>(Qb,Kb,Vb,PKg,PQg,amask,Ctxb);
    // output proj + residual, LN1
    gemm_kernel<2><<<gQ,blk,0,stream>>>(Ctxb, Wo_l, bo_l, Hb, Xb, NTOK,NHID,NHID);
    ln_kernel<<<NTOK,blk,0,stream>>>(Xb, g1_l, b1_l, H1);
    // FFN
    gemm_kernel<1><<<gF1,blk,0,stream>>>(H1, Wi_l, bi_l, nullptr, FFb, NTOK,NFF,NHID);
    gemm_kernel<2><<<gQ,blk,0,stream>>>(FFb, Wo2_l, bo2_l, H1, Xb, NTOK,NHID,NFF);
    // LN2: last layer writes the final output directly
    float* dst = (l==NL-1) ? (float*)d_out : Hb;
    ln_kernel<<<NTOK,blk,0,stream>>>(Xb, g2_l, b2_l, dst);
  }
}